// Round 21
// baseline (69.778 us; speedup 1.0000x reference)
//
#include <hip/hip_runtime.h>

#define N_NODES 50000
#define F_IN 64
#define F_OUT 128
#define N_EDGES 800000

#define NR 391                       // route ranges of 128 nodes
#define RCAP 2560                    // records per range; mean 2046, +11 sigma
#define CAP 48                       // per-node slots; P(Poisson(16)>=48)~1e-11
#define CPAD 16                      // ints per counter: 1 counter per 64B line
#define NCNT (NR * CPAD)             // 6256 ints = 25,024 B
#define ZERO_BLOCKS 7
#define WCONV_BLOCKS 64              // 16384 / 256
#define EPT 10                       // edges per route thread
#define RBLK 313                     // route blocks: 313*2560 >= 800000
#define NRT (N_NODES / 16)           // 3125 row-tiles of 16 nodes
#define GBLK 782                     // gemm blocks: 4 row-tiles per wave-set
#define AGG_BLOCKS 3125              // one per 16 nodes (round-18 proven TLP)

typedef __attribute__((ext_vector_type(8))) short bf16x8;   // 8 bf16 = 4 VGPR
typedef __attribute__((ext_vector_type(4))) float f32x4;
typedef __attribute__((ext_vector_type(2))) float f32x2;

__device__ __forceinline__ unsigned short f2bf(float f) {
  unsigned u = __float_as_uint(f);
  unsigned r = u + 0x7FFF + ((u >> 16) & 1);   // round-to-nearest-even
  return (unsigned short)(r >> 16);
}
__device__ __forceinline__ float bf2f(unsigned short h) {
  return __uint_as_float((unsigned)h << 16);
}
__device__ __forceinline__ bf16x8 cvt8(float4 p, float4 q) {
  bf16x8 r;
  r[0] = (short)f2bf(p.x); r[1] = (short)f2bf(p.y);
  r[2] = (short)f2bf(p.z); r[3] = (short)f2bf(p.w);
  r[4] = (short)f2bf(q.x); r[5] = (short)f2bf(q.y);
  r[6] = (short)f2bf(q.z); r[7] = (short)f2bf(q.w);
  return r;
}
#define L4(p) (*(const float4*)(p))

// ---------------------------------------------------------------------------
// Init: zero ccnt (own kernel — round-11: rocclr fill is pathological) and
// fold W into Wcb[256][64] bf16 (row j<128 -> W1[j]-W2[j], else W2[j-128]).
// ---------------------------------------------------------------------------
__global__ __launch_bounds__(256) void init_kernel(
    const float* __restrict__ W, int4* __restrict__ ccnt4,
    unsigned short* __restrict__ Wcb) {
  const int bid = blockIdx.x;
  const int tid = threadIdx.x;
  if (bid < ZERO_BLOCKS) {
    int i = bid * 256 + tid;
    if (i < NCNT / 4) ccnt4[i] = make_int4(0, 0, 0, 0);
    return;
  }
  int idx = (bid - ZERO_BLOCKS) * 256 + tid;   // 0..16383
  int j = idx >> 6, k = idx & 63;
  float v = (j < F_OUT)
                ? W[j * (2 * F_IN) + k] - W[j * (2 * F_IN) + F_IN + k]
                : W[(j - F_OUT) * (2 * F_IN) + F_IN + k];
  Wcb[idx] = f2bf(v);
}

// ---------------------------------------------------------------------------
// Fused route + gemm.
//  blocks [0, RBLK): LDS-histogram two-phase reservation route
//    (~121K global atomics vs 800K — breaks the measured ~23 G/s
//    returning-atomic wall of rounds 3/7/10/13).
//  blocks [RBLK, +GBLK): MFMA projections, ROUND-21: 4 row-tiles per wave
//    (16 x-loads in flight, 32 MFMAs/wave, W fragments amortized 4x;
//    rounds 19->20 showed the role is x-load-latency-bound: 2-tile MLP
//    bought -3.9us). Grid 313+782=1095 blocks, fully co-resident.
//    Operand-swapped mfma_f32_16x16x32_bf16 (round-10 proven): node=lane&15,
//    wcol = ct*16 + 4*(lane>>4) + reg. Q stored OCP fp8 e4m3 via HW
//    cvt_pk_fp8_f32 (round-19 proven: halves aggregate gather bytes).
// ---------------------------------------------------------------------------
__global__ __launch_bounds__(256) void route_gemm_kernel(
    const float* __restrict__ x, const unsigned short* __restrict__ Wcb,
    const float* __restrict__ b, const unsigned int* __restrict__ eraw,
    unsigned short* __restrict__ Pb, unsigned char* __restrict__ Qf8,
    int* __restrict__ ccnt, unsigned int* __restrict__ chunks) {
  __shared__ int hist[NR];
  __shared__ int cur[NR];
  __shared__ int gbase[NR];
  const int tid = threadIdx.x;
  const int bid = blockIdx.x;

  if (bid < RBLK) {
    // int64 LE (values < 2^31) -> odd 32-bit words all zero; int32 random
    // indices -> all-zero probability ~ (2e-5)^4.
    const bool is64 = ((eraw[1] | eraw[3] | eraw[5] | eraw[7]) == 0u);

    for (int i = tid; i < NR; i += 256) { hist[i] = 0; cur[i] = 0; gbase[i] = 0; }
    __syncthreads();

    int er[EPT], ec[EPT];
#pragma unroll
    for (int i = 0; i < EPT; ++i) {
      int e = bid * (EPT * 256) + i * 256 + tid;
      if (e < N_EDGES) {
        er[i] = (int)(is64 ? eraw[2 * (size_t)e] : eraw[e]);
        ec[i] = (int)(is64 ? eraw[2 * ((size_t)N_EDGES + e)] : eraw[N_EDGES + e]);
        atomicAdd(&hist[er[i] >> 7], 1);
      } else {
        er[i] = -1; ec[i] = 0;
      }
    }
    __syncthreads();

    for (int i = tid; i < NR; i += 256) {   // full NR coverage (round-15 fix)
      int h = hist[i];
      if (h > 0) gbase[i] = atomicAdd(&ccnt[i * CPAD], h);
    }
    __syncthreads();

#pragma unroll
    for (int i = 0; i < EPT; ++i) {
      if (er[i] >= 0) {
        int g = er[i] >> 7;
        int pos = gbase[g] + atomicAdd(&cur[g], 1);
        if (pos >= 0 && pos < RCAP)
          chunks[(size_t)g * RCAP + pos] =
              ((unsigned)er[i] << 16) | (unsigned)ec[i];
      }
    }
    return;
  }

  const int gb = bid - RBLK;           // 0..781
  const int rtb = gb * 4;              // tiles rtb..rtb+3 (3125 = 4*781+1)
  const int lane = tid & 63;
  const int w = tid >> 6;              // ct quarter: cts [4w, 4w+4)
  const int l15 = lane & 15;
  const int hi = lane >> 4;            // 0..3
  const int lk = hi * 8;

  // Stage all 16 x-loads up front (4x MLP vs round-19's single tile),
  // then convert. Full unroll keeps every index compile-time (rule #20).
  bf16x8 xa0[4], xa1[4];
  float4 s0[4], s1[4], s2[4], s3[4];
#pragma unroll
  for (int t = 0; t < 4; ++t) {
    const int rt = min(rtb + t, NRT - 1);   // clamp: tail block re-reads
    const float* xr = x + ((size_t)rt * 16 + l15) * F_IN;
    s0[t] = L4(xr + lk);      s1[t] = L4(xr + lk + 4);
    s2[t] = L4(xr + 32 + lk); s3[t] = L4(xr + 36 + lk);
  }
#pragma unroll
  for (int t = 0; t < 4; ++t) {
    xa0[t] = cvt8(s0[t], s1[t]);
    xa1[t] = cvt8(s2[t], s3[t]);
  }

#pragma unroll
  for (int q = 0; q < 4; ++q) {
    const int ct = w * 4 + q;
    const unsigned short* wrow = Wcb + (size_t)(ct * 16 + l15) * F_IN;
    bf16x8 wb0 = *(const bf16x8*)(wrow + lk);
    bf16x8 wb1 = *(const bf16x8*)(wrow + 32 + lk);

    f32x4 binit;
    if (ct < 8) {
      float4 bv = *(const float4*)&b[ct * 16 + hi * 4];
      binit[0] = bv.x; binit[1] = bv.y; binit[2] = bv.z; binit[3] = bv.w;
    } else {
      binit[0] = 0.f; binit[1] = 0.f; binit[2] = 0.f; binit[3] = 0.f;
    }
    const int col = (ct & 7) * 16 + hi * 4;

#pragma unroll
    for (int t = 0; t < 4; ++t) {
      if (rtb + t >= NRT) continue;          // tail guard
      f32x4 acc = binit;
      acc = __builtin_amdgcn_mfma_f32_16x16x32_bf16(wb0, xa0[t], acc, 0, 0, 0);
      acc = __builtin_amdgcn_mfma_f32_16x16x32_bf16(wb1, xa1[t], acc, 0, 0, 0);
      const int node = (rtb + t) * 16 + l15;
      if (ct < 8) {
        ushort4 o = {f2bf(acc[0]), f2bf(acc[1]), f2bf(acc[2]), f2bf(acc[3])};
        *(ushort4*)&Pb[(size_t)node * F_OUT + col] = o;
      } else {
        int pk = __builtin_amdgcn_cvt_pk_fp8_f32(acc[0], acc[1], 0, false);
        pk = __builtin_amdgcn_cvt_pk_fp8_f32(acc[2], acc[3], pk, true);
        *(unsigned int*)&Qf8[(size_t)node * F_OUT + col] = (unsigned)pk;
      }
    }
  }
}

// ---------------------------------------------------------------------------
// Aggregate (round-18 TLP + round-19 fp8 Q, frozen: 3125 blocks x 16 nodes,
// Pb prefetch, 8-deep fp8 gather unroll decoded with HW cvt_pk_f32_fp8).
// ---------------------------------------------------------------------------
__global__ __launch_bounds__(256) void aggregate_kernel(
    const unsigned short* __restrict__ Pb, const unsigned char* __restrict__ Qf8,
    const unsigned int* __restrict__ chunks, const int* __restrict__ ccnt,
    float* __restrict__ out) {
  __shared__ int lcnt[16];
  __shared__ unsigned short lslot[16][CAP];   // 1536 B
  const int B = blockIdx.x;
  const int g = B >> 3;
  const int tid = threadIdx.x;
  const int node0 = B * 16;        // 50000 = 3125*16 -> always in range
  const int lane = tid & 31;

  // Pb prefetch: latency hides under the scan phase.
  const int n0 = node0 + (tid >> 5);
  const int n1 = node0 + 8 + (tid >> 5);
  ushort4 pb0 = ((const ushort4*)(Pb + (size_t)n0 * F_OUT))[lane];
  ushort4 pb1 = ((const ushort4*)(Pb + (size_t)n1 * F_OUT))[lane];

  if (tid < 16) lcnt[tid] = 0;
  __syncthreads();

  {
    const int m = min(ccnt[g * CPAD], RCAP);
    const unsigned int* ch = chunks + (size_t)g * RCAP;
    for (int i = tid; i < m; i += 256) {
      unsigned rec = ch[i];
      int r = (int)(rec >> 16);
      if ((r >> 4) == B) {
        int rl = r & 15;
        int pos = atomicAdd(&lcnt[rl], 1);
        if (pos < CAP) lslot[rl][pos] = (unsigned short)(rec & 0xFFFF);
      }
    }
  }
  __syncthreads();

#pragma unroll
  for (int s = 0; s < 2; ++s) {
    const int rl = s * 8 + (tid >> 5);
    const int n = node0 + rl;
    const ushort4 pb = s ? pb1 : pb0;
    const float px = bf2f(pb.x), py = bf2f(pb.y), pz = bf2f(pb.z), pw = bf2f(pb.w);

    const int deg = lcnt[rl];
    const int m = min(deg, CAP);
    const unsigned short* sl = lslot[rl];
    const int qoff = lane * 4;

    float4 acc = make_float4(0.f, 0.f, 0.f, 0.f);
    int j = 0;
    for (; j + 8 <= m; j += 8) {
      unsigned w0 = *(const unsigned*)(Qf8 + (size_t)sl[j + 0] * F_OUT + qoff);
      unsigned w1 = *(const unsigned*)(Qf8 + (size_t)sl[j + 1] * F_OUT + qoff);
      unsigned w2 = *(const unsigned*)(Qf8 + (size_t)sl[j + 2] * F_OUT + qoff);
      unsigned w3 = *(const unsigned*)(Qf8 + (size_t)sl[j + 3] * F_OUT + qoff);
      unsigned w4 = *(const unsigned*)(Qf8 + (size_t)sl[j + 4] * F_OUT + qoff);
      unsigned w5 = *(const unsigned*)(Qf8 + (size_t)sl[j + 5] * F_OUT + qoff);
      unsigned w6 = *(const unsigned*)(Qf8 + (size_t)sl[j + 6] * F_OUT + qoff);
      unsigned w7 = *(const unsigned*)(Qf8 + (size_t)sl[j + 7] * F_OUT + qoff);
#define ACCUM(wq)                                                      \
      {                                                                \
        f32x2 lo = __builtin_amdgcn_cvt_pk_f32_fp8((int)(wq), false);  \
        f32x2 hv = __builtin_amdgcn_cvt_pk_f32_fp8((int)(wq), true);   \
        acc.x += fmaxf(px + lo[0], 0.f); acc.y += fmaxf(py + lo[1], 0.f); \
        acc.z += fmaxf(pz + hv[0], 0.f); acc.w += fmaxf(pw + hv[1], 0.f); \
      }
      ACCUM(w0) ACCUM(w1) ACCUM(w2) ACCUM(w3)
      ACCUM(w4) ACCUM(w5) ACCUM(w6) ACCUM(w7)
    }
    for (; j + 4 <= m; j += 4) {
      unsigned w0 = *(const unsigned*)(Qf8 + (size_t)sl[j + 0] * F_OUT + qoff);
      unsigned w1 = *(const unsigned*)(Qf8 + (size_t)sl[j + 1] * F_OUT + qoff);
      unsigned w2 = *(const unsigned*)(Qf8 + (size_t)sl[j + 2] * F_OUT + qoff);
      unsigned w3 = *(const unsigned*)(Qf8 + (size_t)sl[j + 3] * F_OUT + qoff);
      ACCUM(w0) ACCUM(w1) ACCUM(w2) ACCUM(w3)
    }
    for (; j < m; ++j) {
      unsigned wq = *(const unsigned*)(Qf8 + (size_t)sl[j] * F_OUT + qoff);
      ACCUM(wq)
    }
#undef ACCUM

    const float inv = 1.0f / (float)(deg > 1 ? deg : 1);
    float4 o = make_float4(acc.x * inv, acc.y * inv, acc.z * inv, acc.w * inv);
    ((float4*)(out + (size_t)n * F_OUT))[lane] = o;
  }
}

extern "C" void kernel_launch(void* const* d_in, const int* in_sizes, int n_in,
                              void* d_out, int out_size, void* d_ws, size_t ws_size,
                              hipStream_t stream) {
  const float* x = (const float*)d_in[0];
  const unsigned int* eraw = (const unsigned int*)d_in[1];
  const float* W = (const float*)d_in[2];
  const float* b = (const float*)d_in[3];
  float* out = (float*)d_out;

  char* ws = (char*)d_ws;
  unsigned short* Pb   = (unsigned short*)(ws);             // 12,800,000 B
  unsigned char* Qf8   = (unsigned char*)(ws + 12800000);   //  6,400,000 B
  int* ccnt            = (int*)(ws + 19200000);             //     25,024 B
  unsigned int* chunks = (unsigned int*)(ws + 19232000);    //  4,003,840 B
  unsigned short* Wcb  = (unsigned short*)(ws + 23240000);  //     32,768 B

  init_kernel<<<ZERO_BLOCKS + WCONV_BLOCKS, 256, 0, stream>>>(
      W, (int4*)ccnt, Wcb);
  route_gemm_kernel<<<RBLK + GBLK, 256, 0, stream>>>(
      x, Wcb, b, eraw, Pb, Qf8, ccnt, chunks);
  aggregate_kernel<<<AGG_BLOCKS, 256, 0, stream>>>(Pb, Qf8, chunks, ccnt, out);
}

// Round 22
// 67.315 us; speedup vs baseline: 1.0366x; 1.0366x over previous
//
#include <hip/hip_runtime.h>

#define N_NODES 50000
#define F_IN 64
#define F_OUT 128
#define N_EDGES 800000

#define NR 391                       // route ranges of 128 nodes
#define RCAP 2560                    // records per range; mean 2046, +11 sigma
#define CAP 48                       // per-node slots; P(Poisson(16)>=48)~1e-11
#define CPAD 16                      // ints per counter: 1 counter per 64B line
#define NCNT (NR * CPAD)             // 6256 ints = 25,024 B
#define ZERO_BLOCKS 7
#define WCONV_BLOCKS 64              // 16384 / 256
#define EPT 10                       // edges per route thread
#define RBLK 313                     // route blocks: 313*2560 >= 800000
#define NRT (N_NODES / 16)           // 3125 row-tiles of 16 nodes
#define GBLK 1563                    // gemm blocks: 2 row-tiles per wave-set (r20 optimum)
#define AGG_BLOCKS 3125              // one per 16 nodes (round-18 proven TLP)

typedef __attribute__((ext_vector_type(8))) short bf16x8;   // 8 bf16 = 4 VGPR
typedef __attribute__((ext_vector_type(4))) float f32x4;
typedef __attribute__((ext_vector_type(2))) float f32x2;

__device__ __forceinline__ unsigned short f2bf(float f) {
  unsigned u = __float_as_uint(f);
  unsigned r = u + 0x7FFF + ((u >> 16) & 1);   // round-to-nearest-even
  return (unsigned short)(r >> 16);
}
__device__ __forceinline__ float bf2f(unsigned short h) {
  return __uint_as_float((unsigned)h << 16);
}
__device__ __forceinline__ bf16x8 cvt8(float4 p, float4 q) {
  bf16x8 r;
  r[0] = (short)f2bf(p.x); r[1] = (short)f2bf(p.y);
  r[2] = (short)f2bf(p.z); r[3] = (short)f2bf(p.w);
  r[4] = (short)f2bf(q.x); r[5] = (short)f2bf(q.y);
  r[6] = (short)f2bf(q.z); r[7] = (short)f2bf(q.w);
  return r;
}
#define L4(p) (*(const float4*)(p))

// ---------------------------------------------------------------------------
// ROUND-22: revert to the round-20 optimum (67.3us). Round-21's 4-tile MLP
// regressed (+2.5us: 16 staged float4 pushed gemm VGPR past the occupancy
// knee — the round-8 trade). 2-tile is the proven sweet spot.
// ---------------------------------------------------------------------------

// ---------------------------------------------------------------------------
// Init: zero ccnt (own kernel — round-11: rocclr fill is pathological) and
// fold W into Wcb[256][64] bf16 (row j<128 -> W1[j]-W2[j], else W2[j-128]).
// ---------------------------------------------------------------------------
__global__ __launch_bounds__(256) void init_kernel(
    const float* __restrict__ W, int4* __restrict__ ccnt4,
    unsigned short* __restrict__ Wcb) {
  const int bid = blockIdx.x;
  const int tid = threadIdx.x;
  if (bid < ZERO_BLOCKS) {
    int i = bid * 256 + tid;
    if (i < NCNT / 4) ccnt4[i] = make_int4(0, 0, 0, 0);
    return;
  }
  int idx = (bid - ZERO_BLOCKS) * 256 + tid;   // 0..16383
  int j = idx >> 6, k = idx & 63;
  float v = (j < F_OUT)
                ? W[j * (2 * F_IN) + k] - W[j * (2 * F_IN) + F_IN + k]
                : W[(j - F_OUT) * (2 * F_IN) + F_IN + k];
  Wcb[idx] = f2bf(v);
}

// ---------------------------------------------------------------------------
// Fused route + gemm.
//  blocks [0, RBLK): LDS-histogram two-phase reservation route
//    (~121K global atomics vs 800K — breaks the measured ~23 G/s
//    returning-atomic wall of rounds 3/7/10/13).
//  blocks [RBLK, +GBLK): MFMA projections, 2 row-tiles per wave (round-20
//    proven: 8 x-loads in flight, 16 MFMAs/wave, W fragments reused).
//    Operand-swapped mfma_f32_16x16x32_bf16 (round-10 proven): node=lane&15,
//    wcol = ct*16 + 4*(lane>>4) + reg. Q stored OCP fp8 e4m3 via HW
//    cvt_pk_fp8_f32 (round-19 proven: halves aggregate gather bytes).
// ---------------------------------------------------------------------------
__global__ __launch_bounds__(256) void route_gemm_kernel(
    const float* __restrict__ x, const unsigned short* __restrict__ Wcb,
    const float* __restrict__ b, const unsigned int* __restrict__ eraw,
    unsigned short* __restrict__ Pb, unsigned char* __restrict__ Qf8,
    int* __restrict__ ccnt, unsigned int* __restrict__ chunks) {
  __shared__ int hist[NR];
  __shared__ int cur[NR];
  __shared__ int gbase[NR];
  const int tid = threadIdx.x;
  const int bid = blockIdx.x;

  if (bid < RBLK) {
    // int64 LE (values < 2^31) -> odd 32-bit words all zero; int32 random
    // indices -> all-zero probability ~ (2e-5)^4.
    const bool is64 = ((eraw[1] | eraw[3] | eraw[5] | eraw[7]) == 0u);

    for (int i = tid; i < NR; i += 256) { hist[i] = 0; cur[i] = 0; gbase[i] = 0; }
    __syncthreads();

    int er[EPT], ec[EPT];
#pragma unroll
    for (int i = 0; i < EPT; ++i) {
      int e = bid * (EPT * 256) + i * 256 + tid;
      if (e < N_EDGES) {
        er[i] = (int)(is64 ? eraw[2 * (size_t)e] : eraw[e]);
        ec[i] = (int)(is64 ? eraw[2 * ((size_t)N_EDGES + e)] : eraw[N_EDGES + e]);
        atomicAdd(&hist[er[i] >> 7], 1);
      } else {
        er[i] = -1; ec[i] = 0;
      }
    }
    __syncthreads();

    for (int i = tid; i < NR; i += 256) {   // full NR coverage (round-15 fix)
      int h = hist[i];
      if (h > 0) gbase[i] = atomicAdd(&ccnt[i * CPAD], h);
    }
    __syncthreads();

#pragma unroll
    for (int i = 0; i < EPT; ++i) {
      if (er[i] >= 0) {
        int g = er[i] >> 7;
        int pos = gbase[g] + atomicAdd(&cur[g], 1);
        if (pos >= 0 && pos < RCAP)
          chunks[(size_t)g * RCAP + pos] =
              ((unsigned)er[i] << 16) | (unsigned)ec[i];
      }
    }
    return;
  }

  const int gb = bid - RBLK;           // 0..1562
  const int rt0 = gb * 2;
  const int rt1 = rt0 + 1;
  const bool has1 = (rt1 < NRT);       // 3125 is odd: last block single-tile
  const int lane = tid & 63;
  const int w = tid >> 6;              // ct quarter: cts [4w, 4w+4)
  const int l15 = lane & 15;
  const int hi = lane >> 4;            // 0..3
  const int lk = hi * 8;

  // Issue all 8 x-loads up front (2x MLP vs single-tile round-19).
  const float* xr0 = x + ((size_t)rt0 * 16 + l15) * F_IN;
  const float* xr1 = x + ((size_t)(has1 ? rt1 : rt0) * 16 + l15) * F_IN;
  float4 a00 = L4(xr0 + lk),      a01 = L4(xr0 + lk + 4);
  float4 a02 = L4(xr0 + 32 + lk), a03 = L4(xr0 + 36 + lk);
  float4 a10 = L4(xr1 + lk),      a11 = L4(xr1 + lk + 4);
  float4 a12 = L4(xr1 + 32 + lk), a13 = L4(xr1 + 36 + lk);
  bf16x8 xa0_0 = cvt8(a00, a01), xa1_0 = cvt8(a02, a03);
  bf16x8 xa0_1 = cvt8(a10, a11), xa1_1 = cvt8(a12, a13);
  const int node0 = rt0 * 16 + l15;
  const int node1 = node0 + 16;

#pragma unroll
  for (int q = 0; q < 4; ++q) {
    const int ct = w * 4 + q;
    const unsigned short* wrow = Wcb + (size_t)(ct * 16 + l15) * F_IN;
    bf16x8 wb0 = *(const bf16x8*)(wrow + lk);
    bf16x8 wb1 = *(const bf16x8*)(wrow + 32 + lk);

    f32x4 acc0, acc1;
    if (ct < 8) {
      float4 bv = *(const float4*)&b[ct * 16 + hi * 4];
      acc0[0] = bv.x; acc0[1] = bv.y; acc0[2] = bv.z; acc0[3] = bv.w;
    } else {
      acc0[0] = 0.f; acc0[1] = 0.f; acc0[2] = 0.f; acc0[3] = 0.f;
    }
    acc1 = acc0;
    acc0 = __builtin_amdgcn_mfma_f32_16x16x32_bf16(wb0, xa0_0, acc0, 0, 0, 0);
    acc0 = __builtin_amdgcn_mfma_f32_16x16x32_bf16(wb1, xa1_0, acc0, 0, 0, 0);
    acc1 = __builtin_amdgcn_mfma_f32_16x16x32_bf16(wb0, xa0_1, acc1, 0, 0, 0);
    acc1 = __builtin_amdgcn_mfma_f32_16x16x32_bf16(wb1, xa1_1, acc1, 0, 0, 0);

    const int col = (ct & 7) * 16 + hi * 4;
    if (ct < 8) {
      ushort4 o0 = {f2bf(acc0[0]), f2bf(acc0[1]), f2bf(acc0[2]), f2bf(acc0[3])};
      *(ushort4*)&Pb[(size_t)node0 * F_OUT + col] = o0;
      if (has1) {
        ushort4 o1 = {f2bf(acc1[0]), f2bf(acc1[1]), f2bf(acc1[2]), f2bf(acc1[3])};
        *(ushort4*)&Pb[(size_t)node1 * F_OUT + col] = o1;
      }
    } else {
      int pk0 = __builtin_amdgcn_cvt_pk_fp8_f32(acc0[0], acc0[1], 0, false);
      pk0 = __builtin_amdgcn_cvt_pk_fp8_f32(acc0[2], acc0[3], pk0, true);
      *(unsigned int*)&Qf8[(size_t)node0 * F_OUT + col] = (unsigned)pk0;
      if (has1) {
        int pk1 = __builtin_amdgcn_cvt_pk_fp8_f32(acc1[0], acc1[1], 0, false);
        pk1 = __builtin_amdgcn_cvt_pk_fp8_f32(acc1[2], acc1[3], pk1, true);
        *(unsigned int*)&Qf8[(size_t)node1 * F_OUT + col] = (unsigned)pk1;
      }
    }
  }
}

// ---------------------------------------------------------------------------
// Aggregate (round-18 TLP + round-19 fp8 Q, frozen: 3125 blocks x 16 nodes,
// Pb prefetch, 8-deep fp8 gather unroll decoded with HW cvt_pk_f32_fp8).
// ---------------------------------------------------------------------------
__global__ __launch_bounds__(256) void aggregate_kernel(
    const unsigned short* __restrict__ Pb, const unsigned char* __restrict__ Qf8,
    const unsigned int* __restrict__ chunks, const int* __restrict__ ccnt,
    float* __restrict__ out) {
  __shared__ int lcnt[16];
  __shared__ unsigned short lslot[16][CAP];   // 1536 B
  const int B = blockIdx.x;
  const int g = B >> 3;
  const int tid = threadIdx.x;
  const int node0 = B * 16;        // 50000 = 3125*16 -> always in range
  const int lane = tid & 31;

  // Pb prefetch: latency hides under the scan phase.
  const int n0 = node0 + (tid >> 5);
  const int n1 = node0 + 8 + (tid >> 5);
  ushort4 pb0 = ((const ushort4*)(Pb + (size_t)n0 * F_OUT))[lane];
  ushort4 pb1 = ((const ushort4*)(Pb + (size_t)n1 * F_OUT))[lane];

  if (tid < 16) lcnt[tid] = 0;
  __syncthreads();

  {
    const int m = min(ccnt[g * CPAD], RCAP);
    const unsigned int* ch = chunks + (size_t)g * RCAP;
    for (int i = tid; i < m; i += 256) {
      unsigned rec = ch[i];
      int r = (int)(rec >> 16);
      if ((r >> 4) == B) {
        int rl = r & 15;
        int pos = atomicAdd(&lcnt[rl], 1);
        if (pos < CAP) lslot[rl][pos] = (unsigned short)(rec & 0xFFFF);
      }
    }
  }
  __syncthreads();

#pragma unroll
  for (int s = 0; s < 2; ++s) {
    const int rl = s * 8 + (tid >> 5);
    const int n = node0 + rl;
    const ushort4 pb = s ? pb1 : pb0;
    const float px = bf2f(pb.x), py = bf2f(pb.y), pz = bf2f(pb.z), pw = bf2f(pb.w);

    const int deg = lcnt[rl];
    const int m = min(deg, CAP);
    const unsigned short* sl = lslot[rl];
    const int qoff = lane * 4;

    float4 acc = make_float4(0.f, 0.f, 0.f, 0.f);
    int j = 0;
    for (; j + 8 <= m; j += 8) {
      unsigned w0 = *(const unsigned*)(Qf8 + (size_t)sl[j + 0] * F_OUT + qoff);
      unsigned w1 = *(const unsigned*)(Qf8 + (size_t)sl[j + 1] * F_OUT + qoff);
      unsigned w2 = *(const unsigned*)(Qf8 + (size_t)sl[j + 2] * F_OUT + qoff);
      unsigned w3 = *(const unsigned*)(Qf8 + (size_t)sl[j + 3] * F_OUT + qoff);
      unsigned w4 = *(const unsigned*)(Qf8 + (size_t)sl[j + 4] * F_OUT + qoff);
      unsigned w5 = *(const unsigned*)(Qf8 + (size_t)sl[j + 5] * F_OUT + qoff);
      unsigned w6 = *(const unsigned*)(Qf8 + (size_t)sl[j + 6] * F_OUT + qoff);
      unsigned w7 = *(const unsigned*)(Qf8 + (size_t)sl[j + 7] * F_OUT + qoff);
#define ACCUM(wq)                                                      \
      {                                                                \
        f32x2 lo = __builtin_amdgcn_cvt_pk_f32_fp8((int)(wq), false);  \
        f32x2 hv = __builtin_amdgcn_cvt_pk_f32_fp8((int)(wq), true);   \
        acc.x += fmaxf(px + lo[0], 0.f); acc.y += fmaxf(py + lo[1], 0.f); \
        acc.z += fmaxf(pz + hv[0], 0.f); acc.w += fmaxf(pw + hv[1], 0.f); \
      }
      ACCUM(w0) ACCUM(w1) ACCUM(w2) ACCUM(w3)
      ACCUM(w4) ACCUM(w5) ACCUM(w6) ACCUM(w7)
    }
    for (; j + 4 <= m; j += 4) {
      unsigned w0 = *(const unsigned*)(Qf8 + (size_t)sl[j + 0] * F_OUT + qoff);
      unsigned w1 = *(const unsigned*)(Qf8 + (size_t)sl[j + 1] * F_OUT + qoff);
      unsigned w2 = *(const unsigned*)(Qf8 + (size_t)sl[j + 2] * F_OUT + qoff);
      unsigned w3 = *(const unsigned*)(Qf8 + (size_t)sl[j + 3] * F_OUT + qoff);
      ACCUM(w0) ACCUM(w1) ACCUM(w2) ACCUM(w3)
    }
    for (; j < m; ++j) {
      unsigned wq = *(const unsigned*)(Qf8 + (size_t)sl[j] * F_OUT + qoff);
      ACCUM(wq)
    }
#undef ACCUM

    const float inv = 1.0f / (float)(deg > 1 ? deg : 1);
    float4 o = make_float4(acc.x * inv, acc.y * inv, acc.z * inv, acc.w * inv);
    ((float4*)(out + (size_t)n * F_OUT))[lane] = o;
  }
}

extern "C" void kernel_launch(void* const* d_in, const int* in_sizes, int n_in,
                              void* d_out, int out_size, void* d_ws, size_t ws_size,
                              hipStream_t stream) {
  const float* x = (const float*)d_in[0];
  const unsigned int* eraw = (const unsigned int*)d_in[1];
  const float* W = (const float*)d_in[2];
  const float* b = (const float*)d_in[3];
  float* out = (float*)d_out;

  char* ws = (char*)d_ws;
  unsigned short* Pb   = (unsigned short*)(ws);             // 12,800,000 B
  unsigned char* Qf8   = (unsigned char*)(ws + 12800000);   //  6,400,000 B
  int* ccnt            = (int*)(ws + 19200000);             //     25,024 B
  unsigned int* chunks = (unsigned int*)(ws + 19232000);    //  4,003,840 B
  unsigned short* Wcb  = (unsigned short*)(ws + 23240000);  //     32,768 B

  init_kernel<<<ZERO_BLOCKS + WCONV_BLOCKS, 256, 0, stream>>>(
      W, (int4*)ccnt, Wcb);
  route_gemm_kernel<<<RBLK + GBLK, 256, 0, stream>>>(
      x, Wcb, b, eraw, Pb, Qf8, ccnt, chunks);
  aggregate_kernel<<<AGG_BLOCKS, 256, 0, stream>>>(Pb, Qf8, chunks, ccnt, out);
}